// Round 1
// 330.032 us; speedup vs baseline: 1.0656x; 1.0656x over previous
//
#include <hip/hip_runtime.h>

#define Bb 8
#define Nn 8192
#define Hh 256
#define NUP 2048
#define NDOWN (Nn - NUP)
#define MM 5
#define EPB (NDOWN * MM)   // edges per batch = 30720
#define NCX 16
#define NCY 16
#define NCZ 16
#define NCELL (NCX * NCY * NCZ)   // 4096 3D cells
#define KP 288             // padded K for the feat GEMM (256 h + sl,score,1,pad)
#define LDA 36             // LDS row stride (bf16) for A/B tiles

typedef short v8s __attribute__((ext_vector_type(8)));
typedef float v4f __attribute__((ext_vector_type(4)));

#define INFKEY 0x7F800000FFFFFFFFull

// fp32 -> bf16 round-to-nearest-even
__device__ __forceinline__ unsigned short bfc(float f) {
    unsigned u = __float_as_uint(f);
    return (unsigned short)((u + 0x7FFFu + ((u >> 16) & 1u)) >> 16);
}

// Find the bin (descending order) where the kth-largest element lands.
template <int NB>
__device__ void find_kth_bin(const int* hist, int kth, int tid,
                             int* wsumA, int* res, int* out_bin, int* out_cntgt) {
    constexpr int PER = NB / 1024;
    int ln = tid & 63, wv = tid >> 6;
    int b0 = NB - 1 - PER * tid;
    int c0 = hist[b0];
    int c1 = (PER == 2) ? hist[b0 - 1] : 0;
    int tot = c0 + c1;
    int x = tot;
    #pragma unroll
    for (int off = 1; off < 64; off <<= 1) {
        int y = __shfl_up(x, off);
        if (ln >= off) x += y;
    }
    if (ln == 63) wsumA[wv] = x;
    __syncthreads();
    int wbase = 0;
    for (int w = 0; w < wv; w++) wbase += wsumA[w];
    int excl = wbase + x - tot;
    if (excl < kth && excl + c0 >= kth) { res[0] = b0; res[1] = excl; }
    else if (PER == 2 && excl + c0 < kth && excl + c0 + c1 >= kth) { res[0] = b0 - 1; res[1] = excl + c0; }
    __syncthreads();
    *out_bin = res[0];
    *out_cntgt = res[1];
}

// Kernel A: exact top-NUP selection via 3-level radix select, fused compaction
// + up_local inverse map + deg zeroing.
__global__ __launch_bounds__(1024) void select_kernel(
        const float* __restrict__ scores, const float* __restrict__ sl,
        int* __restrict__ mask, float4* __restrict__ upc,
        int* __restrict__ up_local, int* __restrict__ deg) {
    int b = blockIdx.x;
    int tid = threadIdx.x;
    int ln = tid & 63, wv = tid >> 6;
    __shared__ int hist[2048];
    __shared__ int wsumA[16], wsumB[16];
    __shared__ int res[2];
    __shared__ int sbase[2];
    const float* s = scores + (size_t)b * Nn;

    deg[b * NUP + tid] = 0;
    deg[b * NUP + 1024 + tid] = 0;

    hist[tid] = 0; hist[tid + 1024] = 0;
    __syncthreads();
    for (int t = tid; t < Nn; t += 1024)
        atomicAdd(&hist[__float_as_uint(s[t]) >> 21], 1);
    __syncthreads();
    int B1, gt1;
    find_kth_bin<2048>(hist, NUP, tid, wsumA, res, &B1, &gt1);
    int slots1 = NUP - gt1;

    hist[tid] = 0; hist[tid + 1024] = 0;
    __syncthreads();
    for (int t = tid; t < Nn; t += 1024) {
        unsigned u = __float_as_uint(s[t]);
        if ((int)(u >> 21) == B1) atomicAdd(&hist[(u >> 10) & 0x7FF], 1);
    }
    __syncthreads();
    int B2, gt2;
    find_kth_bin<2048>(hist, slots1, tid, wsumA, res, &B2, &gt2);
    int slots2 = slots1 - gt2;
    unsigned hi22 = ((unsigned)B1 << 11) | (unsigned)B2;

    hist[tid] = 0; hist[tid + 1024] = 0;
    __syncthreads();
    for (int t = tid; t < Nn; t += 1024) {
        unsigned u = __float_as_uint(s[t]);
        if ((u >> 10) == hi22) atomicAdd(&hist[u & 0x3FF], 1);
    }
    __syncthreads();
    int B3, gt3;
    find_kth_bin<1024>(hist, slots2, tid, wsumA, res, &B3, &gt3);
    int slots_eq = slots2 - gt3;
    unsigned T = (hi22 << 10) | (unsigned)B3;

    if (tid == 0) { sbase[0] = 0; sbase[1] = 0; }
    __syncthreads();
    for (int t0 = 0; t0 < Nn; t0 += 1024) {
        int node = t0 + tid;
        int g = b * Nn + node;
        unsigned u = __float_as_uint(s[node]);
        bool eq = (u == T);
        unsigned long long bal = __ballot(eq);
        unsigned long long lmask = (1ull << ln) - 1ull;
        int pre = __popcll(bal & lmask);
        if (ln == 0) wsumA[wv] = __popcll(bal);
        __syncthreads();
        int eqbase = sbase[0];
        for (int w = 0; w < wv; w++) eqbase += wsumA[w];
        bool up = (u > T) || (eq && (eqbase + pre) < slots_eq);
        unsigned long long bal2 = __ballot(up);
        int pre2 = __popcll(bal2 & lmask);
        if (ln == 0) wsumB[wv] = __popcll(bal2);
        __syncthreads();
        int upbase = sbase[1];
        for (int w = 0; w < wv; w++) upbase += wsumB[w];
        if (up) {
            float4 c;
            c.x = sl[(size_t)g * 3 + 0];
            c.y = sl[(size_t)g * 3 + 1];
            c.z = sl[(size_t)g * 3 + 2];
            c.w = __int_as_float(node);
            upc[b * NUP + upbase + pre2] = c;
            up_local[g] = upbase + pre2;
        }
        mask[g] = up ? 1 : 0;
        __syncthreads();
        if (tid == 0) {
            int se = 0, su = 0;
            for (int w = 0; w < 16; w++) { se += wsumA[w]; su += wsumB[w]; }
            sbase[0] += se; sbase[1] += su;
        }
        __syncthreads();
    }
}

// Block-wide exclusive scan over 4096 bins (1024 threads x 4 bins each).
// hist in, exclusive prefix out in cur. Returns total (uniform).
__device__ __forceinline__ int scan_bins_4096(const int* hist, int* cur,
                                              int tid, int* wsum) {
    int ln = tid & 63, wv = tid >> 6;
    int i0 = 4 * tid;
    int h0 = hist[i0], h1 = hist[i0 + 1], h2 = hist[i0 + 2], h3 = hist[i0 + 3];
    int s = h0 + h1 + h2 + h3;
    int x = s;
    #pragma unroll
    for (int off = 1; off < 64; off <<= 1) {
        int y = __shfl_up(x, off);
        if (ln >= off) x += y;
    }
    if (ln == 63) wsum[wv] = x;
    __syncthreads();
    int base = 0;
    for (int w = 0; w < wv; w++) base += wsum[w];
    int excl = base + x - s;
    cur[i0] = excl; cur[i0 + 1] = excl + h0;
    cur[i0 + 2] = excl + h0 + h1; cur[i0 + 3] = excl + h0 + h1 + h2;
    int tot = 0;
    for (int w = 0; w < 16; w++) tot += wsum[w];
    __syncthreads();
    return tot;
}

// Kernel P: per-batch 3D spatial prep. Bucket ups into 16x16x16 (x,y,z) cells
// (counting sort -> upg/cellptr/grid params) and counting-sort downs by home
// 3D cell -> dord.
__global__ __launch_bounds__(1024) void prep_kernel(
        const float* __restrict__ sl, const int* __restrict__ mask,
        const float4* __restrict__ upc, float4* __restrict__ upg,
        int* __restrict__ cellptr, float4* __restrict__ gridp,
        float4* __restrict__ dord) {
    int b = blockIdx.x;
    int tid = threadIdx.x;
    int ln = tid & 63, wv = tid >> 6;
    __shared__ float red[16][6];
    __shared__ int wsum[16];
    __shared__ int hist[NCELL];
    __shared__ int cur[NCELL];
    __shared__ float gpar[6];

    float4 u0 = upc[b * NUP + tid];
    float4 u1 = upc[b * NUP + 1024 + tid];
    float mnx = fminf(u0.x, u1.x), mxx = fmaxf(u0.x, u1.x);
    float mny = fminf(u0.y, u1.y), mxy = fmaxf(u0.y, u1.y);
    float mnz = fminf(u0.z, u1.z), mxz = fmaxf(u0.z, u1.z);
    #pragma unroll
    for (int off = 32; off; off >>= 1) {
        mnx = fminf(mnx, __shfl_down(mnx, off));
        mxx = fmaxf(mxx, __shfl_down(mxx, off));
        mny = fminf(mny, __shfl_down(mny, off));
        mxy = fmaxf(mxy, __shfl_down(mxy, off));
        mnz = fminf(mnz, __shfl_down(mnz, off));
        mxz = fmaxf(mxz, __shfl_down(mxz, off));
    }
    if (ln == 0) {
        red[wv][0] = mnx; red[wv][1] = mxx; red[wv][2] = mny;
        red[wv][3] = mxy; red[wv][4] = mnz; red[wv][5] = mxz;
    }
    hist[tid] = 0; hist[tid + 1024] = 0; hist[tid + 2048] = 0; hist[tid + 3072] = 0;
    __syncthreads();
    if (tid == 0) {
        float ax = red[0][0], cx = red[0][1], ay = red[0][2];
        float cy = red[0][3], az = red[0][4], cz = red[0][5];
        for (int w = 1; w < 16; w++) {
            ax = fminf(ax, red[w][0]); cx = fmaxf(cx, red[w][1]);
            ay = fminf(ay, red[w][2]); cy = fmaxf(cy, red[w][3]);
            az = fminf(az, red[w][4]); cz = fmaxf(cz, red[w][5]);
        }
        gpar[0] = ax; gpar[1] = fmaxf(cx - ax, 1e-20f) * (1.0f / NCX) * 1.0000002f;
        gpar[2] = ay; gpar[3] = fmaxf(cy - ay, 1e-20f) * (1.0f / NCY) * 1.0000002f;
        gpar[4] = az; gpar[5] = fmaxf(cz - az, 1e-20f) * (1.0f / NCZ) * 1.0000002f;
        gridp[2 * b]     = make_float4(gpar[0], gpar[1], gpar[2], gpar[3]);
        gridp[2 * b + 1] = make_float4(gpar[4], gpar[5], 0.f, 0.f);
    }
    __syncthreads();
    float ax = gpar[0], wx = gpar[1], ay = gpar[2], wy = gpar[3], az = gpar[4], wz = gpar[5];
    int c0x = min(NCX - 1, max(0, (int)((u0.x - ax) / wx)));
    int c0y = min(NCY - 1, max(0, (int)((u0.y - ay) / wy)));
    int c0z = min(NCZ - 1, max(0, (int)((u0.z - az) / wz)));
    int c1x = min(NCX - 1, max(0, (int)((u1.x - ax) / wx)));
    int c1y = min(NCY - 1, max(0, (int)((u1.y - ay) / wy)));
    int c1z = min(NCZ - 1, max(0, (int)((u1.z - az) / wz)));
    int cid0 = (c0z * NCY + c0y) * NCX + c0x;
    int cid1 = (c1z * NCY + c1y) * NCX + c1x;
    atomicAdd(&hist[cid0], 1);
    atomicAdd(&hist[cid1], 1);
    __syncthreads();
    int tot = scan_bins_4096(hist, cur, tid, wsum);
    {
        int i0 = 4 * tid;
        int cb = b * (NCELL + 1);
        cellptr[cb + i0] = cur[i0];
        cellptr[cb + i0 + 1] = cur[i0 + 1];
        cellptr[cb + i0 + 2] = cur[i0 + 2];
        cellptr[cb + i0 + 3] = cur[i0 + 3];
        if (tid == 0) cellptr[cb + NCELL] = tot;
    }
    __syncthreads();   // cellptr reads of cur done before atomics mutate cur
    int s0 = atomicAdd(&cur[cid0], 1); upg[b * NUP + s0] = u0;
    int s1 = atomicAdd(&cur[cid1], 1); upg[b * NUP + s1] = u1;

    // ---- downs: counting-sort by home 3D cell
    __syncthreads();
    hist[tid] = 0; hist[tid + 1024] = 0; hist[tid + 2048] = 0; hist[tid + 3072] = 0;
    __syncthreads();
    for (int t = tid; t < Nn; t += 1024) {
        int g = b * Nn + t;
        if (!mask[g]) {
            float x = sl[(size_t)g * 3 + 0];
            float y = sl[(size_t)g * 3 + 1];
            float z = sl[(size_t)g * 3 + 2];
            int cx = min(NCX - 1, max(0, (int)((x - ax) / wx)));
            int cy = min(NCY - 1, max(0, (int)((y - ay) / wy)));
            int cz = min(NCZ - 1, max(0, (int)((z - az) / wz)));
            atomicAdd(&hist[(cz * NCY + cy) * NCX + cx], 1);
        }
    }
    __syncthreads();
    scan_bins_4096(hist, cur, tid, wsum);
    for (int t = tid; t < Nn; t += 1024) {
        int g = b * Nn + t;
        if (!mask[g]) {
            float x = sl[(size_t)g * 3 + 0];
            float y = sl[(size_t)g * 3 + 1];
            float z = sl[(size_t)g * 3 + 2];
            int cx = min(NCX - 1, max(0, (int)((x - ax) / wx)));
            int cy = min(NCY - 1, max(0, (int)((y - ay) / wy)));
            int cz = min(NCZ - 1, max(0, (int)((z - az) / wz)));
            int slot = atomicAdd(&cur[(cz * NCY + cy) * NCX + cx], 1);
            float4 e; e.x = x; e.y = y; e.z = z; e.w = __int_as_float(t);
            dord[b * NDOWN + slot] = e;
        }
    }
}

// Kernel C: exact 5-NN on a 3D cell grid. 256-thread block = 64 cell-sorted
// downs x 4 candidate-subset threads. Range-list pager: all cell ranges of a
// rect (minus already-scanned inner rect) are prefix-scanned into LDS, then
// streamed through a 256-slot stage with full pages (2 barriers / 256 cands).
// Phase A: home bbox +-1 in 3D, expand shells until every down has >=5.
// Phase B: T = per-down merged 5th-best -> block-max radius -> 3D target rect
// minus scanned rect. u64 (d2<<32|id) keys = exact (d2,idx).
__global__ __launch_bounds__(256) void knn2d(
        const float4* __restrict__ upg, const int* __restrict__ cellptr,
        const float4* __restrict__ gridp, const float4* __restrict__ dord,
        const int* __restrict__ up_local, int* __restrict__ knn,
        int* __restrict__ deg) {
    int b = blockIdx.y;
    int tid = threadIdx.x;
    int sub = tid >> 6, dn = tid & 63;
    __shared__ float4 stage[256];
    __shared__ unsigned long long part[20 * 64];  // [(l*5+m)*64 + dn]
    __shared__ int fc[4][64];
    __shared__ float redf[8];
    __shared__ int flag;
    __shared__ int rStart[512];
    __shared__ int rCum[513];
    __shared__ int wsumS[4];

    float4 gp1 = gridp[2 * b], gp2 = gridp[2 * b + 1];
    float4 d = dord[b * NDOWN + blockIdx.x * 64 + dn];
    float xd = d.x, yd = d.y, zd = d.z;
    int node = __float_as_int(d.w);
    int cx = min(NCX - 1, max(0, (int)((xd - gp1.x) / gp1.y)));
    int cy = min(NCY - 1, max(0, (int)((yd - gp1.z) / gp1.w)));
    int cz = min(NCZ - 1, max(0, (int)((zd - gp2.x) / gp2.y)));

    unsigned long long bd[MM];
    #pragma unroll
    for (int m = 0; m < MM; m++) bd[m] = INFKEY;

    auto ins = [&](unsigned long long* L, unsigned long long cand) {
        #pragma unroll
        for (int m = 0; m < MM; m++) {
            bool lt = cand < L[m];
            unsigned long long lo = lt ? cand : L[m];
            unsigned long long hi = lt ? L[m] : cand;
            L[m] = lo; cand = hi;
        }
    };

    const int cb = b * (NCELL + 1);

    // Build range list for cells in outer rect minus inner rect (inner may be
    // empty: ix0>ix1). Block-uniform args. Returns total up count (uniform).
    auto buildScan = [&](int ox0, int ox1, int oy0, int oy1, int oz0, int oz1,
                         int ix0, int ix1, int iy0, int iy1, int iz0, int iz1) -> int {
        int ny = oy1 - oy0 + 1;
        int rows = ny * (oz1 - oz0 + 1);   // <= 256
        __syncthreads();                   // prior users of rStart/rCum/wsumS done
        int l0 = 0, l1 = 0, p0 = 0, p1 = 0;
        if (tid < rows) {
            int rz = oz0 + tid / ny, ry = oy0 + tid % ny;
            int base = (rz * NCY + ry) * NCX;
            int a1v = ox1, bb0 = 1, bb1 = 0;
            if (rz >= iz0 && rz <= iz1 && ry >= iy0 && ry <= iy1) {
                a1v = min(ox1, ix0 - 1);
                bb0 = max(ox0, ix1 + 1); bb1 = ox1;
            }
            if (ox0 <= a1v) { p0 = cellptr[cb + base + ox0]; l0 = cellptr[cb + base + a1v + 1] - p0; }
            if (bb0 <= bb1) { p1 = cellptr[cb + base + bb0]; l1 = cellptr[cb + base + bb1 + 1] - p1; }
        }
        int s = l0 + l1, x = s;
        #pragma unroll
        for (int off = 1; off < 64; off <<= 1) {
            int y = __shfl_up(x, off);
            if (dn >= off) x += y;
        }
        if (dn == 63) wsumS[sub] = x;
        __syncthreads();
        int basex = 0;
        for (int w = 0; w < sub; w++) basex += wsumS[w];
        int excl = basex + x - s;
        rStart[2 * tid] = p0;     rCum[2 * tid] = excl;
        rStart[2 * tid + 1] = p1; rCum[2 * tid + 1] = excl + l0;
        int tot = wsumS[0] + wsumS[1] + wsumS[2] + wsumS[3];
        if (tid == 0) rCum[512] = tot;
        __syncthreads();
        return tot;
    };

    auto pageScan = [&](int tot) {
        for (int pg = 0; pg < tot; pg += 256) {
            __syncthreads();   // previous page fully consumed
            int idx = pg + tid;
            if (idx < tot) {
                int lo = 0, hi = 511;
                while (lo < hi) {
                    int mid = (lo + hi) >> 1;
                    if (rCum[mid + 1] <= idx) lo = mid + 1; else hi = mid;
                }
                stage[tid] = upg[b * NUP + rStart[lo] + (idx - rCum[lo])];
            }
            __syncthreads();
            int cnt = min(256, tot - pg);
            for (int j = sub; j < cnt; j += 4) {
                float4 c = stage[j];
                float dx = c.x - xd, dy = c.y - yd, dz = c.z - zd;
                float d2 = fmaf(dx, dx, fmaf(dy, dy, dz * dz));
                unsigned long long key =
                    ((unsigned long long)__float_as_uint(d2) << 32) |
                    (unsigned long long)(unsigned)__float_as_int(c.w);
                if (key < bd[MM - 1]) ins(bd, key);   // cheap reject on common path
            }
        }
    };

    auto rmin = [&](int v) {
        #pragma unroll
        for (int o = 32; o; o >>= 1) v = min(v, __shfl_xor(v, o));
        return v;
    };
    auto rmax = [&](int v) {
        #pragma unroll
        for (int o = 32; o; o >>= 1) v = max(v, __shfl_xor(v, o));
        return v;
    };
    // (waves are sub-uniform, every wave's dn spans 0..63 -> same result)
    int sxL = max(0, rmin(cx) - 1), sxH = min(NCX - 1, rmax(cx) + 1);
    int syL = max(0, rmin(cy) - 1), syH = min(NCY - 1, rmax(cy) + 1);
    int szL = max(0, rmin(cz) - 1), szH = min(NCZ - 1, rmax(cz) + 1);

    pageScan(buildScan(sxL, sxH, syL, syH, szL, szH, 1, 0, 1, 0, 1, 0));

    // expansion until every down has >=5 found (block-wide)
    while (true) {
        __syncthreads();
        if (tid == 0) flag = 0;
        int f = 0;
        #pragma unroll
        for (int m = 0; m < MM; m++) f += (bd[m] != INFKEY) ? 1 : 0;
        fc[sub][dn] = f;
        __syncthreads();
        if (sub == 0) {
            int t4 = fc[0][dn] + fc[1][dn] + fc[2][dn] + fc[3][dn];
            if (t4 < MM) atomicAdd(&flag, 1);
        }
        __syncthreads();
        if (flag == 0) break;
        if (sxL == 0 && sxH == NCX - 1 && syL == 0 && syH == NCY - 1 &&
            szL == 0 && szH == NCZ - 1) break;
        int nxL = max(0, sxL - 1), nxH = min(NCX - 1, sxH + 1);
        int nyL = max(0, syL - 1), nyH = min(NCY - 1, syH + 1);
        int nzL = max(0, szL - 1), nzH = min(NCZ - 1, szH + 1);
        pageScan(buildScan(nxL, nxH, nyL, nyH, nzL, nzH,
                           sxL, sxH, syL, syH, szL, szH));
        sxL = nxL; sxH = nxH; syL = nyL; syH = nyH; szL = nzL; szH = nzH;
    }

    // Phase B bound: merged 5th-best per down -> block max radius + down bbox
    __syncthreads();
    #pragma unroll
    for (int m = 0; m < MM; m++) part[(sub * MM + m) * 64 + dn] = bd[m];
    __syncthreads();
    if (sub == 0) {
        unsigned long long fin[MM];
        #pragma unroll
        for (int m = 0; m < MM; m++) fin[m] = 0xFFFFFFFFFFFFFFFFull;
        #pragma unroll
        for (int l = 0; l < 4; l++)
            #pragma unroll
            for (int m = 0; m < MM; m++) ins(fin, part[(l * MM + m) * 64 + dn]);
        float T = __uint_as_float((unsigned)(fin[MM - 1] >> 32));
        float Tm = T, xl = xd, xh = xd, yl = yd, yh = yd, zl = zd, zh = zd;
        #pragma unroll
        for (int off = 32; off; off >>= 1) {
            Tm = fmaxf(Tm, __shfl_xor(Tm, off));
            xl = fminf(xl, __shfl_xor(xl, off));
            xh = fmaxf(xh, __shfl_xor(xh, off));
            yl = fminf(yl, __shfl_xor(yl, off));
            yh = fmaxf(yh, __shfl_xor(yh, off));
            zl = fminf(zl, __shfl_xor(zl, off));
            zh = fmaxf(zh, __shfl_xor(zh, off));
        }
        if (dn == 0) {
            redf[0] = Tm; redf[1] = xl; redf[2] = xh; redf[3] = yl;
            redf[4] = yh; redf[5] = zl; redf[6] = zh;
        }
    }
    __syncthreads();
    float r = sqrtf(redf[0]);
    int txL = min(NCX - 1, max(0, (int)((redf[1] - r - gp1.x) / gp1.y)));
    int txH = min(NCX - 1, max(0, (int)((redf[2] + r - gp1.x) / gp1.y)));
    int tyL = min(NCY - 1, max(0, (int)((redf[3] - r - gp1.z) / gp1.w)));
    int tyH = min(NCY - 1, max(0, (int)((redf[4] + r - gp1.z) / gp1.w)));
    int tzL = min(NCZ - 1, max(0, (int)((redf[5] - r - gp2.x) / gp2.y)));
    int tzH = min(NCZ - 1, max(0, (int)((redf[6] + r - gp2.x) / gp2.y)));
    pageScan(buildScan(txL, txH, tyL, tyH, tzL, tzH,
                       sxL, sxH, syL, syH, szL, szH));

    // final merge + outputs
    __syncthreads();
    #pragma unroll
    for (int m = 0; m < MM; m++) part[(sub * MM + m) * 64 + dn] = bd[m];
    __syncthreads();
    if (sub == 0) {
        unsigned long long fin[MM];
        #pragma unroll
        for (int m = 0; m < MM; m++) fin[m] = 0xFFFFFFFFFFFFFFFFull;
        #pragma unroll
        for (int l = 0; l < 4; l++)
            #pragma unroll
            for (int m = 0; m < MM; m++) ins(fin, part[(l * MM + m) * 64 + dn]);
        int g = b * Nn + node;
        #pragma unroll
        for (int m = 0; m < MM; m++) {
            int nid = (int)(unsigned)(fin[m] & 0xFFFFFFFFull);
            knn[g * MM + m] = nid;
            atomicAdd(&deg[b * NUP + up_local[b * Nn + nid]], 1);
        }
    }
}

// Kernel W: Wt[n][k] = bf16 of W-ext^T.
__global__ void wt_kernel(const float* __restrict__ W, const float* __restrict__ bias,
                          unsigned short* __restrict__ Wt) {
    int n = blockIdx.x;
    int k = threadIdx.x;
    Wt[n * KP + k] = bfc(W[(size_t)k * Hh + n]);
    if (k < KP - 256) {
        int kk = 256 + k;
        unsigned short v = 0;
        if (kk < 260)       v = bfc(W[(size_t)kk * Hh + n]);
        else if (kk == 260) v = bfc(bias[n]);
        Wt[n * KP + kk] = v;
    }
}

// Kernel B: feat GEMM via bf16 MFMA. C[128m x 128n] per block, 4 waves of 64x64.
__global__ void feat_mfma(const float* __restrict__ h, const float* __restrict__ sl,
                          const float* __restrict__ sc, const unsigned short* __restrict__ Wt,
                          float* __restrict__ out) {
    int b = blockIdx.z;
    int m0 = blockIdx.x * 128;
    int n0 = blockIdx.y * 128;
    int tid = threadIdx.x;
    __shared__ unsigned short Al[128 * LDA];
    __shared__ unsigned short Bl[128 * LDA];
    int wid = tid >> 6, lane = tid & 63;
    int wm = (wid & 1) * 64, wn = (wid >> 1) * 64;
    int lm = lane & 15, quad = lane >> 4;
    v4f acc[4][4];
    #pragma unroll
    for (int i = 0; i < 4; i++)
        #pragma unroll
        for (int j = 0; j < 4; j++)
            acc[i][j] = (v4f){0.f, 0.f, 0.f, 0.f};
    const float* Ab = h + ((size_t)b * Nn + m0) * Hh;
    for (int t = 0; t < 9; t++) {
        int k0 = t * 32;
        __syncthreads();
        if (t < 8) {
            #pragma unroll
            for (int q = 0; q < 4; q++) {
                int e = q * 256 + tid;
                int row = e >> 3, kq = e & 7;
                float4 v = *(const float4*)(Ab + (size_t)row * Hh + k0 + kq * 4);
                ushort4 o = make_ushort4(bfc(v.x), bfc(v.y), bfc(v.z), bfc(v.w));
                *(ushort4*)(Al + row * LDA + kq * 4) = o;
            }
        } else if (tid < 128) {
            int row = tid;
            int g = b * Nn + m0 + row;
            unsigned short r[32];
            #pragma unroll
            for (int k = 0; k < 32; k++) r[k] = 0;
            r[0] = bfc(sl[(size_t)g * 3 + 0]);
            r[1] = bfc(sl[(size_t)g * 3 + 1]);
            r[2] = bfc(sl[(size_t)g * 3 + 2]);
            r[3] = bfc(sc[g]);
            r[4] = 0x3F80;  // 1.0 (bias column)
            #pragma unroll
            for (int q = 0; q < 8; q++)
                *(ushort4*)(Al + row * LDA + q * 4) =
                    make_ushort4(r[q * 4], r[q * 4 + 1], r[q * 4 + 2], r[q * 4 + 3]);
        }
        #pragma unroll
        for (int q = 0; q < 4; q++) {
            int e = q * 256 + tid;
            int n = e >> 3, kq = e & 7;
            ushort4 v = *(const ushort4*)(Wt + (size_t)(n0 + n) * KP + k0 + kq * 4);
            *(ushort4*)(Bl + n * LDA + kq * 4) = v;
        }
        __syncthreads();
        v8s af[4], bfr[4];
        #pragma unroll
        for (int i = 0; i < 4; i++)
            af[i] = *(const v8s*)(Al + (wm + i * 16 + lm) * LDA + quad * 8);
        #pragma unroll
        for (int j = 0; j < 4; j++)
            bfr[j] = *(const v8s*)(Bl + (wn + j * 16 + lm) * LDA + quad * 8);
        #pragma unroll
        for (int i = 0; i < 4; i++)
            #pragma unroll
            for (int j = 0; j < 4; j++)
                acc[i][j] = __builtin_amdgcn_mfma_f32_16x16x32_bf16(af[i], bfr[j], acc[i][j], 0, 0, 0);
    }
    #pragma unroll
    for (int i = 0; i < 4; i++) {
        #pragma unroll
        for (int r = 0; r < 4; r++) {
            int row = m0 + wm + i * 16 + quad * 4 + r;
            size_t base = ((size_t)b * Nn + row) * Hh + n0 + wn + lm;
            #pragma unroll
            for (int j = 0; j < 4; j++)
                out[base + j * 16] = acc[i][j][r];
        }
    }
}

// CSR build: per-batch exclusive scan of deg -> rowptr (+ cursor copy).
__global__ __launch_bounds__(1024) void csr_scan(const int* __restrict__ deg,
                                                 int* __restrict__ rowptr,
                                                 int* __restrict__ cursor) {
    int b = blockIdx.x;
    int tid = threadIdx.x;
    int ln = tid & 63, wv = tid >> 6;
    __shared__ int wsum[16];
    int d0 = deg[b * NUP + 2 * tid], d1 = deg[b * NUP + 2 * tid + 1];
    int s = d0 + d1;
    int x = s;
    #pragma unroll
    for (int off = 1; off < 64; off <<= 1) {
        int y = __shfl_up(x, off);
        if (ln >= off) x += y;
    }
    if (ln == 63) wsum[wv] = x;
    __syncthreads();
    int base = 0;
    for (int w = 0; w < wv; w++) base += wsum[w];
    int excl = base + x - s;
    rowptr[b * (NUP + 1) + 2 * tid] = excl;
    rowptr[b * (NUP + 1) + 2 * tid + 1] = excl + d0;
    cursor[b * NUP + 2 * tid] = excl;
    cursor[b * NUP + 2 * tid + 1] = excl + d0;
    if (tid == 1023) rowptr[b * (NUP + 1) + NUP] = excl + s;
}

// CSR build: fill edge array (src = batch-local down node id).
__global__ void csr_fill(const int* __restrict__ mask, const int* __restrict__ knn,
                         const int* __restrict__ up_local, int* __restrict__ cursor,
                         int* __restrict__ edges) {
    int b = blockIdx.y;
    int i = blockIdx.x * 256 + threadIdx.x;
    int g = b * Nn + i;
    if (mask[g]) return;
    #pragma unroll
    for (int m = 0; m < MM; m++) {
        int un = knn[g * MM + m];
        int slot = atomicAdd(&cursor[b * NUP + up_local[b * Nn + un]], 1);
        edges[b * EPB + slot] = i;
    }
}

// Kernel D: gather-max. One wave per up node; lanes own 4 cols (float4).
__global__ void gather_kernel(const float4* __restrict__ upc, const int* __restrict__ rowptr,
                              const int* __restrict__ edges, float* __restrict__ out) {
    int b = blockIdx.y;
    int u = blockIdx.x * 4 + (threadIdx.x >> 6);
    int lane = threadIdx.x & 63;
    int node = __float_as_int(upc[b * NUP + u].w);
    int start = rowptr[b * (NUP + 1) + u];
    int end   = rowptr[b * (NUP + 1) + u + 1];
    const int* eb = edges + b * EPB;
    size_t rowbase = (size_t)b * Nn * Hh + (size_t)(lane << 2);
    float4 a0 = make_float4(-3.4e38f, -3.4e38f, -3.4e38f, -3.4e38f);
    float4 a1 = a0;
    int e = start;
    for (; e + 2 <= end; e += 2) {
        int s0 = eb[e], s1 = eb[e + 1];
        float4 v0 = *(const float4*)(out + rowbase + (size_t)s0 * Hh);
        float4 v1 = *(const float4*)(out + rowbase + (size_t)s1 * Hh);
        a0.x = fmaxf(a0.x, v0.x); a0.y = fmaxf(a0.y, v0.y);
        a0.z = fmaxf(a0.z, v0.z); a0.w = fmaxf(a0.w, v0.w);
        a1.x = fmaxf(a1.x, v1.x); a1.y = fmaxf(a1.y, v1.y);
        a1.z = fmaxf(a1.z, v1.z); a1.w = fmaxf(a1.w, v1.w);
    }
    if (e < end) {
        int s0 = eb[e];
        float4 v0 = *(const float4*)(out + rowbase + (size_t)s0 * Hh);
        a0.x = fmaxf(a0.x, v0.x); a0.y = fmaxf(a0.y, v0.y);
        a0.z = fmaxf(a0.z, v0.z); a0.w = fmaxf(a0.w, v0.w);
    }
    float4 r;
    r.x = fmaxf(a0.x, a1.x); r.y = fmaxf(a0.y, a1.y);
    r.z = fmaxf(a0.z, a1.z); r.w = fmaxf(a0.w, a1.w);
    if (start == end) r = make_float4(0.f, 0.f, 0.f, 0.f);
    *(float4*)(out + rowbase + (size_t)node * Hh) = r;
}

// Kernel E: zero down rows, write mask tail.
__global__ void finalize_kernel(const int* __restrict__ mask, float* __restrict__ out) {
    int b = blockIdx.y;
    int node = blockIdx.x * 4 + (threadIdx.x >> 6);
    int g = b * Nn + node;
    int lane = threadIdx.x & 63;
    bool up = mask[g] != 0;
    if (!up)
        *(float4*)(out + (size_t)g * Hh + (lane << 2)) = make_float4(0.f, 0.f, 0.f, 0.f);
    if (lane == 0) out[(size_t)Bb * Nn * Hh + g] = up ? 1.0f : 0.0f;
}

extern "C" void kernel_launch(void* const* d_in, const int* in_sizes, int n_in,
                              void* d_out, int out_size, void* d_ws, size_t ws_size,
                              hipStream_t stream) {
    const float* h    = (const float*)d_in[0];
    const float* sl   = (const float*)d_in[1];
    const float* sc   = (const float*)d_in[2];
    const float* W    = (const float*)d_in[3];
    const float* bias = (const float*)d_in[4];

    char* ws = (char*)d_ws;
    int* mask = (int*)ws;                 ws += (size_t)Bb * Nn * sizeof(int);
    int* knn  = (int*)ws;                 ws += (size_t)Bb * Nn * MM * sizeof(int);
    float4* upc = (float4*)ws;            ws += (size_t)Bb * NUP * sizeof(float4);
    unsigned short* Wt = (unsigned short*)ws; ws += (size_t)Hh * KP * sizeof(unsigned short);
    int* up_local = (int*)ws;             ws += (size_t)Bb * Nn * sizeof(int);
    int* deg = (int*)ws;                  ws += (size_t)Bb * NUP * sizeof(int);
    int* cursor = (int*)ws;               ws += (size_t)Bb * NUP * sizeof(int);
    int* rowptr = (int*)ws;               ws += (size_t)Bb * (NUP + 1) * sizeof(int);
    int* edges = (int*)ws;                ws += (size_t)Bb * EPB * sizeof(int);
    float4* upg = (float4*)ws;            ws += (size_t)Bb * NUP * sizeof(float4);
    int* cellptr = (int*)ws;              ws += (size_t)Bb * (NCELL + 1) * sizeof(int);
    float4* gridp = (float4*)ws;          ws += (size_t)Bb * 2 * sizeof(float4);
    float4* dord = (float4*)ws;           // B*NDOWN float4
    float* outf = (float*)d_out;

    dim3 blk(256);
    select_kernel<<<dim3(Bb), dim3(1024), 0, stream>>>(sc, sl, mask, upc, up_local, deg);
    prep_kernel<<<dim3(Bb), dim3(1024), 0, stream>>>(sl, mask, upc, upg, cellptr, gridp, dord);
    knn2d<<<dim3(NDOWN / 64, Bb), blk, 0, stream>>>(upg, cellptr, gridp, dord,
                                                    up_local, knn, deg);
    csr_scan<<<dim3(Bb), dim3(1024), 0, stream>>>(deg, rowptr, cursor);
    csr_fill<<<dim3(Nn / 256, Bb), blk, 0, stream>>>(mask, knn, up_local, cursor, edges);
    wt_kernel<<<dim3(Hh), blk, 0, stream>>>(W, bias, Wt);
    feat_mfma<<<dim3(Nn / 128, 2, Bb), blk, 0, stream>>>(h, sl, sc, Wt, outf);
    gather_kernel<<<dim3(NUP / 4, Bb), blk, 0, stream>>>(upc, rowptr, edges, outf);
    finalize_kernel<<<dim3(Nn / 4, Bb), blk, 0, stream>>>(mask, outf);
}

// Round 2
// 321.484 us; speedup vs baseline: 1.0939x; 1.0266x over previous
//
#include <hip/hip_runtime.h>

#define Bb 8
#define Nn 8192
#define Hh 256
#define NUP 2048
#define NDOWN (Nn - NUP)
#define MM 5
#define EPB (NDOWN * MM)   // edges per batch = 30720
#define NCX 16
#define NCY 16
#define NCZ 16
#define NCELL (NCX * NCY * NCZ)   // 4096 3D cells
#define KP 288             // padded K for the feat GEMM (256 h + sl,score,1,pad)
#define LDA 36             // LDS row stride (bf16) for A/B tiles

typedef short v8s __attribute__((ext_vector_type(8)));
typedef float v4f __attribute__((ext_vector_type(4)));

#define INFKEY 0x7F800000FFFFFFFFull

// fp32 -> bf16 round-to-nearest-even
__device__ __forceinline__ unsigned short bfc(float f) {
    unsigned u = __float_as_uint(f);
    return (unsigned short)((u + 0x7FFFu + ((u >> 16) & 1u)) >> 16);
}

// spread 4 bits to positions 0,3,6,9
__device__ __forceinline__ int mort4(int v) {
    return (v & 1) | ((v & 2) << 2) | ((v & 4) << 4) | ((v & 8) << 6);
}

// Find the bin (descending order) where the kth-largest element lands.
template <int NB>
__device__ void find_kth_bin(const int* hist, int kth, int tid,
                             int* wsumA, int* res, int* out_bin, int* out_cntgt) {
    constexpr int PER = NB / 1024;
    int ln = tid & 63, wv = tid >> 6;
    int b0 = NB - 1 - PER * tid;
    int c0 = hist[b0];
    int c1 = (PER == 2) ? hist[b0 - 1] : 0;
    int tot = c0 + c1;
    int x = tot;
    #pragma unroll
    for (int off = 1; off < 64; off <<= 1) {
        int y = __shfl_up(x, off);
        if (ln >= off) x += y;
    }
    if (ln == 63) wsumA[wv] = x;
    __syncthreads();
    int wbase = 0;
    for (int w = 0; w < wv; w++) wbase += wsumA[w];
    int excl = wbase + x - tot;
    if (excl < kth && excl + c0 >= kth) { res[0] = b0; res[1] = excl; }
    else if (PER == 2 && excl + c0 < kth && excl + c0 + c1 >= kth) { res[0] = b0 - 1; res[1] = excl + c0; }
    __syncthreads();
    *out_bin = res[0];
    *out_cntgt = res[1];
}

// Kernel A: exact top-NUP selection via 3-level radix select, fused compaction
// + up_local inverse map + deg zeroing.
__global__ __launch_bounds__(1024) void select_kernel(
        const float* __restrict__ scores, const float* __restrict__ sl,
        int* __restrict__ mask, float4* __restrict__ upc,
        int* __restrict__ up_local, int* __restrict__ deg) {
    int b = blockIdx.x;
    int tid = threadIdx.x;
    int ln = tid & 63, wv = tid >> 6;
    __shared__ int hist[2048];
    __shared__ int wsumA[16], wsumB[16];
    __shared__ int res[2];
    __shared__ int sbase[2];
    const float* s = scores + (size_t)b * Nn;

    deg[b * NUP + tid] = 0;
    deg[b * NUP + 1024 + tid] = 0;

    hist[tid] = 0; hist[tid + 1024] = 0;
    __syncthreads();
    for (int t = tid; t < Nn; t += 1024)
        atomicAdd(&hist[__float_as_uint(s[t]) >> 21], 1);
    __syncthreads();
    int B1, gt1;
    find_kth_bin<2048>(hist, NUP, tid, wsumA, res, &B1, &gt1);
    int slots1 = NUP - gt1;

    hist[tid] = 0; hist[tid + 1024] = 0;
    __syncthreads();
    for (int t = tid; t < Nn; t += 1024) {
        unsigned u = __float_as_uint(s[t]);
        if ((int)(u >> 21) == B1) atomicAdd(&hist[(u >> 10) & 0x7FF], 1);
    }
    __syncthreads();
    int B2, gt2;
    find_kth_bin<2048>(hist, slots1, tid, wsumA, res, &B2, &gt2);
    int slots2 = slots1 - gt2;
    unsigned hi22 = ((unsigned)B1 << 11) | (unsigned)B2;

    hist[tid] = 0; hist[tid + 1024] = 0;
    __syncthreads();
    for (int t = tid; t < Nn; t += 1024) {
        unsigned u = __float_as_uint(s[t]);
        if ((u >> 10) == hi22) atomicAdd(&hist[u & 0x3FF], 1);
    }
    __syncthreads();
    int B3, gt3;
    find_kth_bin<1024>(hist, slots2, tid, wsumA, res, &B3, &gt3);
    int slots_eq = slots2 - gt3;
    unsigned T = (hi22 << 10) | (unsigned)B3;

    if (tid == 0) { sbase[0] = 0; sbase[1] = 0; }
    __syncthreads();
    for (int t0 = 0; t0 < Nn; t0 += 1024) {
        int node = t0 + tid;
        int g = b * Nn + node;
        unsigned u = __float_as_uint(s[node]);
        bool eq = (u == T);
        unsigned long long bal = __ballot(eq);
        unsigned long long lmask = (1ull << ln) - 1ull;
        int pre = __popcll(bal & lmask);
        if (ln == 0) wsumA[wv] = __popcll(bal);
        __syncthreads();
        int eqbase = sbase[0];
        for (int w = 0; w < wv; w++) eqbase += wsumA[w];
        bool up = (u > T) || (eq && (eqbase + pre) < slots_eq);
        unsigned long long bal2 = __ballot(up);
        int pre2 = __popcll(bal2 & lmask);
        if (ln == 0) wsumB[wv] = __popcll(bal2);
        __syncthreads();
        int upbase = sbase[1];
        for (int w = 0; w < wv; w++) upbase += wsumB[w];
        if (up) {
            float4 c;
            c.x = sl[(size_t)g * 3 + 0];
            c.y = sl[(size_t)g * 3 + 1];
            c.z = sl[(size_t)g * 3 + 2];
            c.w = __int_as_float(node);
            upc[b * NUP + upbase + pre2] = c;
            up_local[g] = upbase + pre2;
        }
        mask[g] = up ? 1 : 0;
        __syncthreads();
        if (tid == 0) {
            int se = 0, su = 0;
            for (int w = 0; w < 16; w++) { se += wsumA[w]; su += wsumB[w]; }
            sbase[0] += se; sbase[1] += su;
        }
        __syncthreads();
    }
}

// Block-wide exclusive scan over 4096 bins (1024 threads x 4 bins each).
// hist in, exclusive prefix out in cur. Returns total (uniform).
__device__ __forceinline__ int scan_bins_4096(const int* hist, int* cur,
                                              int tid, int* wsum) {
    int ln = tid & 63, wv = tid >> 6;
    int i0 = 4 * tid;
    int h0 = hist[i0], h1 = hist[i0 + 1], h2 = hist[i0 + 2], h3 = hist[i0 + 3];
    int s = h0 + h1 + h2 + h3;
    int x = s;
    #pragma unroll
    for (int off = 1; off < 64; off <<= 1) {
        int y = __shfl_up(x, off);
        if (ln >= off) x += y;
    }
    if (ln == 63) wsum[wv] = x;
    __syncthreads();
    int base = 0;
    for (int w = 0; w < wv; w++) base += wsum[w];
    int excl = base + x - s;
    cur[i0] = excl; cur[i0 + 1] = excl + h0;
    cur[i0 + 2] = excl + h0 + h1; cur[i0 + 3] = excl + h0 + h1 + h2;
    int tot = 0;
    for (int w = 0; w < 16; w++) tot += wsum[w];
    __syncthreads();
    return tot;
}

// Kernel P: per-batch 3D spatial prep. Bucket ups into 16x16x16 (x,y,z) cells
// (counting sort -> upg/cellptr/grid params) and counting-sort downs by home
// cell MORTON code -> dord (compact 3D blobs per 64-down block).
__global__ __launch_bounds__(1024) void prep_kernel(
        const float* __restrict__ sl, const int* __restrict__ mask,
        const float4* __restrict__ upc, float4* __restrict__ upg,
        int* __restrict__ cellptr, float4* __restrict__ gridp,
        float4* __restrict__ dord) {
    int b = blockIdx.x;
    int tid = threadIdx.x;
    int ln = tid & 63, wv = tid >> 6;
    __shared__ float red[16][6];
    __shared__ int wsum[16];
    __shared__ int hist[NCELL];
    __shared__ int cur[NCELL];
    __shared__ float gpar[6];

    float4 u0 = upc[b * NUP + tid];
    float4 u1 = upc[b * NUP + 1024 + tid];
    float mnx = fminf(u0.x, u1.x), mxx = fmaxf(u0.x, u1.x);
    float mny = fminf(u0.y, u1.y), mxy = fmaxf(u0.y, u1.y);
    float mnz = fminf(u0.z, u1.z), mxz = fmaxf(u0.z, u1.z);
    #pragma unroll
    for (int off = 32; off; off >>= 1) {
        mnx = fminf(mnx, __shfl_down(mnx, off));
        mxx = fmaxf(mxx, __shfl_down(mxx, off));
        mny = fminf(mny, __shfl_down(mny, off));
        mxy = fmaxf(mxy, __shfl_down(mxy, off));
        mnz = fminf(mnz, __shfl_down(mnz, off));
        mxz = fmaxf(mxz, __shfl_down(mxz, off));
    }
    if (ln == 0) {
        red[wv][0] = mnx; red[wv][1] = mxx; red[wv][2] = mny;
        red[wv][3] = mxy; red[wv][4] = mnz; red[wv][5] = mxz;
    }
    hist[tid] = 0; hist[tid + 1024] = 0; hist[tid + 2048] = 0; hist[tid + 3072] = 0;
    __syncthreads();
    if (tid == 0) {
        float ax = red[0][0], cx = red[0][1], ay = red[0][2];
        float cy = red[0][3], az = red[0][4], cz = red[0][5];
        for (int w = 1; w < 16; w++) {
            ax = fminf(ax, red[w][0]); cx = fmaxf(cx, red[w][1]);
            ay = fminf(ay, red[w][2]); cy = fmaxf(cy, red[w][3]);
            az = fminf(az, red[w][4]); cz = fmaxf(cz, red[w][5]);
        }
        gpar[0] = ax; gpar[1] = fmaxf(cx - ax, 1e-20f) * (1.0f / NCX) * 1.0000002f;
        gpar[2] = ay; gpar[3] = fmaxf(cy - ay, 1e-20f) * (1.0f / NCY) * 1.0000002f;
        gpar[4] = az; gpar[5] = fmaxf(cz - az, 1e-20f) * (1.0f / NCZ) * 1.0000002f;
        gridp[2 * b]     = make_float4(gpar[0], gpar[1], gpar[2], gpar[3]);
        gridp[2 * b + 1] = make_float4(gpar[4], gpar[5], 0.f, 0.f);
    }
    __syncthreads();
    float ax = gpar[0], wx = gpar[1], ay = gpar[2], wy = gpar[3], az = gpar[4], wz = gpar[5];
    int c0x = min(NCX - 1, max(0, (int)((u0.x - ax) / wx)));
    int c0y = min(NCY - 1, max(0, (int)((u0.y - ay) / wy)));
    int c0z = min(NCZ - 1, max(0, (int)((u0.z - az) / wz)));
    int c1x = min(NCX - 1, max(0, (int)((u1.x - ax) / wx)));
    int c1y = min(NCY - 1, max(0, (int)((u1.y - ay) / wy)));
    int c1z = min(NCZ - 1, max(0, (int)((u1.z - az) / wz)));
    int cid0 = (c0z * NCY + c0y) * NCX + c0x;
    int cid1 = (c1z * NCY + c1y) * NCX + c1x;
    atomicAdd(&hist[cid0], 1);
    atomicAdd(&hist[cid1], 1);
    __syncthreads();
    int tot = scan_bins_4096(hist, cur, tid, wsum);
    {
        int i0 = 4 * tid;
        int cb = b * (NCELL + 1);
        cellptr[cb + i0] = cur[i0];
        cellptr[cb + i0 + 1] = cur[i0 + 1];
        cellptr[cb + i0 + 2] = cur[i0 + 2];
        cellptr[cb + i0 + 3] = cur[i0 + 3];
        if (tid == 0) cellptr[cb + NCELL] = tot;
    }
    __syncthreads();   // cellptr reads of cur done before atomics mutate cur
    int s0 = atomicAdd(&cur[cid0], 1); upg[b * NUP + s0] = u0;
    int s1 = atomicAdd(&cur[cid1], 1); upg[b * NUP + s1] = u1;

    // ---- downs: counting-sort by home-cell Morton code
    __syncthreads();
    hist[tid] = 0; hist[tid + 1024] = 0; hist[tid + 2048] = 0; hist[tid + 3072] = 0;
    __syncthreads();
    for (int t = tid; t < Nn; t += 1024) {
        int g = b * Nn + t;
        if (!mask[g]) {
            float x = sl[(size_t)g * 3 + 0];
            float y = sl[(size_t)g * 3 + 1];
            float z = sl[(size_t)g * 3 + 2];
            int cx = min(NCX - 1, max(0, (int)((x - ax) / wx)));
            int cy = min(NCY - 1, max(0, (int)((y - ay) / wy)));
            int cz = min(NCZ - 1, max(0, (int)((z - az) / wz)));
            atomicAdd(&hist[mort4(cx) | (mort4(cy) << 1) | (mort4(cz) << 2)], 1);
        }
    }
    __syncthreads();
    scan_bins_4096(hist, cur, tid, wsum);
    for (int t = tid; t < Nn; t += 1024) {
        int g = b * Nn + t;
        if (!mask[g]) {
            float x = sl[(size_t)g * 3 + 0];
            float y = sl[(size_t)g * 3 + 1];
            float z = sl[(size_t)g * 3 + 2];
            int cx = min(NCX - 1, max(0, (int)((x - ax) / wx)));
            int cy = min(NCY - 1, max(0, (int)((y - ay) / wy)));
            int cz = min(NCZ - 1, max(0, (int)((z - az) / wz)));
            int slot = atomicAdd(&cur[mort4(cx) | (mort4(cy) << 1) | (mort4(cz) << 2)], 1);
            float4 e; e.x = x; e.y = y; e.z = z; e.w = __int_as_float(t);
            dord[b * NDOWN + slot] = e;
        }
    }
}

// Kernel C: exact 5-NN on a 3D cell grid. 512-thread block = 64 Morton-sorted
// downs x 8 candidate-subset threads. Range-list pager: all cell ranges of a
// rect (minus already-scanned inner rect) are prefix-scanned into LDS, then
// streamed through a 512-slot stage with full pages (2 barriers / 512 cands).
// Phase A: home bbox +-1 in 3D, expand shells until every down has >=5.
// Phase B: T = per-down merged 5th-best -> block-max radius -> 3D target rect
// minus scanned rect. u64 (d2<<32|id) keys = exact (d2,idx).
__global__ __launch_bounds__(512) void knn2d(
        const float4* __restrict__ upg, const int* __restrict__ cellptr,
        const float4* __restrict__ gridp, const float4* __restrict__ dord,
        const int* __restrict__ up_local, int* __restrict__ knn,
        int* __restrict__ deg) {
    int b = blockIdx.y;
    int tid = threadIdx.x;
    int sub = tid >> 6, dn = tid & 63;     // 8 subs x 64 downs
    __shared__ float4 stage[512];
    __shared__ unsigned long long part[40 * 64];  // [(sub*5+m)*64 + dn]
    __shared__ int fc[8][64];
    __shared__ float redf[8];
    __shared__ int flag;
    __shared__ int rStart[512];
    __shared__ int rCum[513];
    __shared__ int wsumS[8];

    float4 gp1 = gridp[2 * b], gp2 = gridp[2 * b + 1];
    float4 d = dord[b * NDOWN + blockIdx.x * 64 + dn];
    float xd = d.x, yd = d.y, zd = d.z;
    int node = __float_as_int(d.w);
    int cx = min(NCX - 1, max(0, (int)((xd - gp1.x) / gp1.y)));
    int cy = min(NCY - 1, max(0, (int)((yd - gp1.z) / gp1.w)));
    int cz = min(NCZ - 1, max(0, (int)((zd - gp2.x) / gp2.y)));

    unsigned long long bd[MM];
    #pragma unroll
    for (int m = 0; m < MM; m++) bd[m] = INFKEY;

    auto ins = [&](unsigned long long* L, unsigned long long cand) {
        #pragma unroll
        for (int m = 0; m < MM; m++) {
            bool lt = cand < L[m];
            unsigned long long lo = lt ? cand : L[m];
            unsigned long long hi = lt ? L[m] : cand;
            L[m] = lo; cand = hi;
        }
    };

    const int cb = b * (NCELL + 1);

    // Build range list for cells in outer rect minus inner rect (inner may be
    // empty: ix0>ix1). Block-uniform args. Returns total up count (uniform).
    auto buildScan = [&](int ox0, int ox1, int oy0, int oy1, int oz0, int oz1,
                         int ix0, int ix1, int iy0, int iy1, int iz0, int iz1) -> int {
        int ny = oy1 - oy0 + 1;
        int rows = ny * (oz1 - oz0 + 1);   // <= 256
        __syncthreads();                   // prior users of rStart/rCum/wsumS done
        int l0 = 0, l1 = 0, p0 = 0, p1 = 0;
        if (tid < rows) {
            int rz = oz0 + tid / ny, ry = oy0 + tid % ny;
            int base = (rz * NCY + ry) * NCX;
            int a1v = ox1, bb0 = 1, bb1 = 0;
            if (rz >= iz0 && rz <= iz1 && ry >= iy0 && ry <= iy1) {
                a1v = min(ox1, ix0 - 1);
                bb0 = max(ox0, ix1 + 1); bb1 = ox1;
            }
            if (ox0 <= a1v) { p0 = cellptr[cb + base + ox0]; l0 = cellptr[cb + base + a1v + 1] - p0; }
            if (bb0 <= bb1) { p1 = cellptr[cb + base + bb0]; l1 = cellptr[cb + base + bb1 + 1] - p1; }
        }
        int s = l0 + l1, x = s;
        #pragma unroll
        for (int off = 1; off < 64; off <<= 1) {
            int y = __shfl_up(x, off);
            if (dn >= off) x += y;
        }
        if (dn == 63) wsumS[sub] = x;
        __syncthreads();
        int basex = 0;
        for (int w = 0; w < sub; w++) basex += wsumS[w];
        int excl = basex + x - s;
        if (tid < 256) {
            rStart[2 * tid] = p0;     rCum[2 * tid] = excl;
            rStart[2 * tid + 1] = p1; rCum[2 * tid + 1] = excl + l0;
        }
        int tot = 0;
        #pragma unroll
        for (int w = 0; w < 8; w++) tot += wsumS[w];
        if (tid == 0) rCum[512] = tot;
        __syncthreads();
        return tot;
    };

    auto pageScan = [&](int tot, int nr) {
        for (int pg = 0; pg < tot; pg += 512) {
            __syncthreads();   // previous page fully consumed
            int idx = pg + tid;
            if (idx < tot) {
                int lo = 0, hi = nr - 1;
                while (lo < hi) {
                    int mid = (lo + hi) >> 1;
                    if (rCum[mid + 1] <= idx) lo = mid + 1; else hi = mid;
                }
                stage[tid] = upg[b * NUP + rStart[lo] + (idx - rCum[lo])];
            }
            __syncthreads();
            int cnt = min(512, tot - pg);
            for (int j = sub; j < cnt; j += 8) {
                float4 c = stage[j];
                float dx = c.x - xd, dy = c.y - yd, dz = c.z - zd;
                float d2 = fmaf(dx, dx, fmaf(dy, dy, dz * dz));
                unsigned long long key =
                    ((unsigned long long)__float_as_uint(d2) << 32) |
                    (unsigned long long)(unsigned)__float_as_int(c.w);
                if (key < bd[MM - 1]) ins(bd, key);   // cheap reject on common path
            }
        }
    };

    auto scanRect = [&](int ox0, int ox1, int oy0, int oy1, int oz0, int oz1,
                        int ix0, int ix1, int iy0, int iy1, int iz0, int iz1) {
        int tot = buildScan(ox0, ox1, oy0, oy1, oz0, oz1,
                            ix0, ix1, iy0, iy1, iz0, iz1);
        int rows = (oy1 - oy0 + 1) * (oz1 - oz0 + 1);
        pageScan(tot, 2 * rows);
    };

    auto rmin = [&](int v) {
        #pragma unroll
        for (int o = 32; o; o >>= 1) v = min(v, __shfl_xor(v, o));
        return v;
    };
    auto rmax = [&](int v) {
        #pragma unroll
        for (int o = 32; o; o >>= 1) v = max(v, __shfl_xor(v, o));
        return v;
    };
    // (waves are sub-uniform, every wave's dn spans 0..63 -> same result)
    int sxL = max(0, rmin(cx) - 1), sxH = min(NCX - 1, rmax(cx) + 1);
    int syL = max(0, rmin(cy) - 1), syH = min(NCY - 1, rmax(cy) + 1);
    int szL = max(0, rmin(cz) - 1), szH = min(NCZ - 1, rmax(cz) + 1);

    scanRect(sxL, sxH, syL, syH, szL, szH, 1, 0, 1, 0, 1, 0);

    // expansion until every down has >=5 found (block-wide)
    while (true) {
        __syncthreads();
        if (tid == 0) flag = 0;
        int f = 0;
        #pragma unroll
        for (int m = 0; m < MM; m++) f += (bd[m] != INFKEY) ? 1 : 0;
        fc[sub][dn] = f;
        __syncthreads();
        if (sub == 0) {
            int t8 = 0;
            #pragma unroll
            for (int l = 0; l < 8; l++) t8 += fc[l][dn];
            if (t8 < MM) atomicAdd(&flag, 1);
        }
        __syncthreads();
        if (flag == 0) break;
        if (sxL == 0 && sxH == NCX - 1 && syL == 0 && syH == NCY - 1 &&
            szL == 0 && szH == NCZ - 1) break;
        int nxL = max(0, sxL - 1), nxH = min(NCX - 1, sxH + 1);
        int nyL = max(0, syL - 1), nyH = min(NCY - 1, syH + 1);
        int nzL = max(0, szL - 1), nzH = min(NCZ - 1, szH + 1);
        scanRect(nxL, nxH, nyL, nyH, nzL, nzH,
                 sxL, sxH, syL, syH, szL, szH);
        sxL = nxL; sxH = nxH; syL = nyL; syH = nyH; szL = nzL; szH = nzH;
    }

    // Phase B bound: merged 5th-best per down -> block max radius + down bbox
    __syncthreads();
    #pragma unroll
    for (int m = 0; m < MM; m++) part[(sub * MM + m) * 64 + dn] = bd[m];
    __syncthreads();
    if (sub == 0) {
        unsigned long long fin[MM];
        #pragma unroll
        for (int m = 0; m < MM; m++) fin[m] = 0xFFFFFFFFFFFFFFFFull;
        #pragma unroll
        for (int l = 0; l < 8; l++)
            #pragma unroll
            for (int m = 0; m < MM; m++) ins(fin, part[(l * MM + m) * 64 + dn]);
        float T = __uint_as_float((unsigned)(fin[MM - 1] >> 32));
        float Tm = T, xl = xd, xh = xd, yl = yd, yh = yd, zl = zd, zh = zd;
        #pragma unroll
        for (int off = 32; off; off >>= 1) {
            Tm = fmaxf(Tm, __shfl_xor(Tm, off));
            xl = fminf(xl, __shfl_xor(xl, off));
            xh = fmaxf(xh, __shfl_xor(xh, off));
            yl = fminf(yl, __shfl_xor(yl, off));
            yh = fmaxf(yh, __shfl_xor(yh, off));
            zl = fminf(zl, __shfl_xor(zl, off));
            zh = fmaxf(zh, __shfl_xor(zh, off));
        }
        if (dn == 0) {
            redf[0] = Tm; redf[1] = xl; redf[2] = xh; redf[3] = yl;
            redf[4] = yh; redf[5] = zl; redf[6] = zh;
        }
    }
    __syncthreads();
    float r = sqrtf(redf[0]);
    int txL = min(NCX - 1, max(0, (int)((redf[1] - r - gp1.x) / gp1.y)));
    int txH = min(NCX - 1, max(0, (int)((redf[2] + r - gp1.x) / gp1.y)));
    int tyL = min(NCY - 1, max(0, (int)((redf[3] - r - gp1.z) / gp1.w)));
    int tyH = min(NCY - 1, max(0, (int)((redf[4] + r - gp1.z) / gp1.w)));
    int tzL = min(NCZ - 1, max(0, (int)((redf[5] - r - gp2.x) / gp2.y)));
    int tzH = min(NCZ - 1, max(0, (int)((redf[6] + r - gp2.x) / gp2.y)));
    scanRect(txL, txH, tyL, tyH, tzL, tzH,
             sxL, sxH, syL, syH, szL, szH);

    // final merge + outputs
    __syncthreads();
    #pragma unroll
    for (int m = 0; m < MM; m++) part[(sub * MM + m) * 64 + dn] = bd[m];
    __syncthreads();
    if (sub == 0) {
        unsigned long long fin[MM];
        #pragma unroll
        for (int m = 0; m < MM; m++) fin[m] = 0xFFFFFFFFFFFFFFFFull;
        #pragma unroll
        for (int l = 0; l < 8; l++)
            #pragma unroll
            for (int m = 0; m < MM; m++) ins(fin, part[(l * MM + m) * 64 + dn]);
        int g = b * Nn + node;
        #pragma unroll
        for (int m = 0; m < MM; m++) {
            int nid = (int)(unsigned)(fin[m] & 0xFFFFFFFFull);
            knn[g * MM + m] = nid;
            atomicAdd(&deg[b * NUP + up_local[b * Nn + nid]], 1);
        }
    }
}

// Kernel W: Wt[n][k] = bf16 of W-ext^T.
__global__ void wt_kernel(const float* __restrict__ W, const float* __restrict__ bias,
                          unsigned short* __restrict__ Wt) {
    int n = blockIdx.x;
    int k = threadIdx.x;
    Wt[n * KP + k] = bfc(W[(size_t)k * Hh + n]);
    if (k < KP - 256) {
        int kk = 256 + k;
        unsigned short v = 0;
        if (kk < 260)       v = bfc(W[(size_t)kk * Hh + n]);
        else if (kk == 260) v = bfc(bias[n]);
        Wt[n * KP + kk] = v;
    }
}

// Kernel B: feat GEMM via bf16 MFMA. C[128m x 128n] per block, 4 waves of 64x64.
__global__ void feat_mfma(const float* __restrict__ h, const float* __restrict__ sl,
                          const float* __restrict__ sc, const unsigned short* __restrict__ Wt,
                          float* __restrict__ out) {
    int b = blockIdx.z;
    int m0 = blockIdx.x * 128;
    int n0 = blockIdx.y * 128;
    int tid = threadIdx.x;
    __shared__ unsigned short Al[128 * LDA];
    __shared__ unsigned short Bl[128 * LDA];
    int wid = tid >> 6, lane = tid & 63;
    int wm = (wid & 1) * 64, wn = (wid >> 1) * 64;
    int lm = lane & 15, quad = lane >> 4;
    v4f acc[4][4];
    #pragma unroll
    for (int i = 0; i < 4; i++)
        #pragma unroll
        for (int j = 0; j < 4; j++)
            acc[i][j] = (v4f){0.f, 0.f, 0.f, 0.f};
    const float* Ab = h + ((size_t)b * Nn + m0) * Hh;
    for (int t = 0; t < 9; t++) {
        int k0 = t * 32;
        __syncthreads();
        if (t < 8) {
            #pragma unroll
            for (int q = 0; q < 4; q++) {
                int e = q * 256 + tid;
                int row = e >> 3, kq = e & 7;
                float4 v = *(const float4*)(Ab + (size_t)row * Hh + k0 + kq * 4);
                ushort4 o = make_ushort4(bfc(v.x), bfc(v.y), bfc(v.z), bfc(v.w));
                *(ushort4*)(Al + row * LDA + kq * 4) = o;
            }
        } else if (tid < 128) {
            int row = tid;
            int g = b * Nn + m0 + row;
            unsigned short r[32];
            #pragma unroll
            for (int k = 0; k < 32; k++) r[k] = 0;
            r[0] = bfc(sl[(size_t)g * 3 + 0]);
            r[1] = bfc(sl[(size_t)g * 3 + 1]);
            r[2] = bfc(sl[(size_t)g * 3 + 2]);
            r[3] = bfc(sc[g]);
            r[4] = 0x3F80;  // 1.0 (bias column)
            #pragma unroll
            for (int q = 0; q < 8; q++)
                *(ushort4*)(Al + row * LDA + q * 4) =
                    make_ushort4(r[q * 4], r[q * 4 + 1], r[q * 4 + 2], r[q * 4 + 3]);
        }
        #pragma unroll
        for (int q = 0; q < 4; q++) {
            int e = q * 256 + tid;
            int n = e >> 3, kq = e & 7;
            ushort4 v = *(const ushort4*)(Wt + (size_t)(n0 + n) * KP + k0 + kq * 4);
            *(ushort4*)(Bl + n * LDA + kq * 4) = v;
        }
        __syncthreads();
        v8s af[4], bfr[4];
        #pragma unroll
        for (int i = 0; i < 4; i++)
            af[i] = *(const v8s*)(Al + (wm + i * 16 + lm) * LDA + quad * 8);
        #pragma unroll
        for (int j = 0; j < 4; j++)
            bfr[j] = *(const v8s*)(Bl + (wn + j * 16 + lm) * LDA + quad * 8);
        #pragma unroll
        for (int i = 0; i < 4; i++)
            #pragma unroll
            for (int j = 0; j < 4; j++)
                acc[i][j] = __builtin_amdgcn_mfma_f32_16x16x32_bf16(af[i], bfr[j], acc[i][j], 0, 0, 0);
    }
    #pragma unroll
    for (int i = 0; i < 4; i++) {
        #pragma unroll
        for (int r = 0; r < 4; r++) {
            int row = m0 + wm + i * 16 + quad * 4 + r;
            size_t base = ((size_t)b * Nn + row) * Hh + n0 + wn + lm;
            #pragma unroll
            for (int j = 0; j < 4; j++)
                out[base + j * 16] = acc[i][j][r];
        }
    }
}

// CSR build: per-batch exclusive scan of deg -> rowptr (+ cursor copy).
__global__ __launch_bounds__(1024) void csr_scan(const int* __restrict__ deg,
                                                 int* __restrict__ rowptr,
                                                 int* __restrict__ cursor) {
    int b = blockIdx.x;
    int tid = threadIdx.x;
    int ln = tid & 63, wv = tid >> 6;
    __shared__ int wsum[16];
    int d0 = deg[b * NUP + 2 * tid], d1 = deg[b * NUP + 2 * tid + 1];
    int s = d0 + d1;
    int x = s;
    #pragma unroll
    for (int off = 1; off < 64; off <<= 1) {
        int y = __shfl_up(x, off);
        if (ln >= off) x += y;
    }
    if (ln == 63) wsum[wv] = x;
    __syncthreads();
    int base = 0;
    for (int w = 0; w < wv; w++) base += wsum[w];
    int excl = base + x - s;
    rowptr[b * (NUP + 1) + 2 * tid] = excl;
    rowptr[b * (NUP + 1) + 2 * tid + 1] = excl + d0;
    cursor[b * NUP + 2 * tid] = excl;
    cursor[b * NUP + 2 * tid + 1] = excl + d0;
    if (tid == 1023) rowptr[b * (NUP + 1) + NUP] = excl + s;
}

// CSR build: fill edge array (src = batch-local down node id).
__global__ void csr_fill(const int* __restrict__ mask, const int* __restrict__ knn,
                         const int* __restrict__ up_local, int* __restrict__ cursor,
                         int* __restrict__ edges) {
    int b = blockIdx.y;
    int i = blockIdx.x * 256 + threadIdx.x;
    int g = b * Nn + i;
    if (mask[g]) return;
    #pragma unroll
    for (int m = 0; m < MM; m++) {
        int un = knn[g * MM + m];
        int slot = atomicAdd(&cursor[b * NUP + up_local[b * Nn + un]], 1);
        edges[b * EPB + slot] = i;
    }
}

// Kernel D: gather-max. One wave per up node; lanes own 4 cols (float4).
__global__ void gather_kernel(const float4* __restrict__ upc, const int* __restrict__ rowptr,
                              const int* __restrict__ edges, float* __restrict__ out) {
    int b = blockIdx.y;
    int u = blockIdx.x * 4 + (threadIdx.x >> 6);
    int lane = threadIdx.x & 63;
    int node = __float_as_int(upc[b * NUP + u].w);
    int start = rowptr[b * (NUP + 1) + u];
    int end   = rowptr[b * (NUP + 1) + u + 1];
    const int* eb = edges + b * EPB;
    size_t rowbase = (size_t)b * Nn * Hh + (size_t)(lane << 2);
    float4 a0 = make_float4(-3.4e38f, -3.4e38f, -3.4e38f, -3.4e38f);
    float4 a1 = a0;
    int e = start;
    for (; e + 2 <= end; e += 2) {
        int s0 = eb[e], s1 = eb[e + 1];
        float4 v0 = *(const float4*)(out + rowbase + (size_t)s0 * Hh);
        float4 v1 = *(const float4*)(out + rowbase + (size_t)s1 * Hh);
        a0.x = fmaxf(a0.x, v0.x); a0.y = fmaxf(a0.y, v0.y);
        a0.z = fmaxf(a0.z, v0.z); a0.w = fmaxf(a0.w, v0.w);
        a1.x = fmaxf(a1.x, v1.x); a1.y = fmaxf(a1.y, v1.y);
        a1.z = fmaxf(a1.z, v1.z); a1.w = fmaxf(a1.w, v1.w);
    }
    if (e < end) {
        int s0 = eb[e];
        float4 v0 = *(const float4*)(out + rowbase + (size_t)s0 * Hh);
        a0.x = fmaxf(a0.x, v0.x); a0.y = fmaxf(a0.y, v0.y);
        a0.z = fmaxf(a0.z, v0.z); a0.w = fmaxf(a0.w, v0.w);
    }
    float4 r;
    r.x = fmaxf(a0.x, a1.x); r.y = fmaxf(a0.y, a1.y);
    r.z = fmaxf(a0.z, a1.z); r.w = fmaxf(a0.w, a1.w);
    if (start == end) r = make_float4(0.f, 0.f, 0.f, 0.f);
    *(float4*)(out + rowbase + (size_t)node * Hh) = r;
}

// Kernel E: zero down rows, write mask tail.
__global__ void finalize_kernel(const int* __restrict__ mask, float* __restrict__ out) {
    int b = blockIdx.y;
    int node = blockIdx.x * 4 + (threadIdx.x >> 6);
    int g = b * Nn + node;
    int lane = threadIdx.x & 63;
    bool up = mask[g] != 0;
    if (!up)
        *(float4*)(out + (size_t)g * Hh + (lane << 2)) = make_float4(0.f, 0.f, 0.f, 0.f);
    if (lane == 0) out[(size_t)Bb * Nn * Hh + g] = up ? 1.0f : 0.0f;
}

extern "C" void kernel_launch(void* const* d_in, const int* in_sizes, int n_in,
                              void* d_out, int out_size, void* d_ws, size_t ws_size,
                              hipStream_t stream) {
    const float* h    = (const float*)d_in[0];
    const float* sl   = (const float*)d_in[1];
    const float* sc   = (const float*)d_in[2];
    const float* W    = (const float*)d_in[3];
    const float* bias = (const float*)d_in[4];

    char* ws = (char*)d_ws;
    int* mask = (int*)ws;                 ws += (size_t)Bb * Nn * sizeof(int);
    int* knn  = (int*)ws;                 ws += (size_t)Bb * Nn * MM * sizeof(int);
    float4* upc = (float4*)ws;            ws += (size_t)Bb * NUP * sizeof(float4);
    unsigned short* Wt = (unsigned short*)ws; ws += (size_t)Hh * KP * sizeof(unsigned short);
    int* up_local = (int*)ws;             ws += (size_t)Bb * Nn * sizeof(int);
    int* deg = (int*)ws;                  ws += (size_t)Bb * NUP * sizeof(int);
    int* cursor = (int*)ws;               ws += (size_t)Bb * NUP * sizeof(int);
    int* rowptr = (int*)ws;               ws += (size_t)Bb * (NUP + 1) * sizeof(int);
    int* edges = (int*)ws;                ws += (size_t)Bb * EPB * sizeof(int);
    float4* upg = (float4*)ws;            ws += (size_t)Bb * NUP * sizeof(float4);
    int* cellptr = (int*)ws;              ws += (size_t)Bb * (NCELL + 1) * sizeof(int);
    float4* gridp = (float4*)ws;          ws += (size_t)Bb * 2 * sizeof(float4);
    float4* dord = (float4*)ws;           // B*NDOWN float4
    float* outf = (float*)d_out;

    dim3 blk(256);
    select_kernel<<<dim3(Bb), dim3(1024), 0, stream>>>(sc, sl, mask, upc, up_local, deg);
    prep_kernel<<<dim3(Bb), dim3(1024), 0, stream>>>(sl, mask, upc, upg, cellptr, gridp, dord);
    knn2d<<<dim3(NDOWN / 64, Bb), dim3(512), 0, stream>>>(upg, cellptr, gridp, dord,
                                                          up_local, knn, deg);
    csr_scan<<<dim3(Bb), dim3(1024), 0, stream>>>(deg, rowptr, cursor);
    csr_fill<<<dim3(Nn / 256, Bb), blk, 0, stream>>>(mask, knn, up_local, cursor, edges);
    wt_kernel<<<dim3(Hh), blk, 0, stream>>>(W, bias, Wt);
    feat_mfma<<<dim3(Nn / 128, 2, Bb), blk, 0, stream>>>(h, sl, sc, Wt, outf);
    gather_kernel<<<dim3(NUP / 4, Bb), blk, 0, stream>>>(upc, rowptr, edges, outf);
    finalize_kernel<<<dim3(Nn / 4, Bb), blk, 0, stream>>>(mask, outf);
}